// Round 6
// baseline (283.858 us; speedup 1.0000x reference)
//
#include <hip/hip_runtime.h>
#include <stdint.h>

#define K_DIM 4096
#define N_DIM 11008
#define NCOL  1376   // N/8

typedef __attribute__((ext_vector_type(4))) float  f32x4;
typedef __attribute__((ext_vector_type(8))) __bf16 bf16x8;

__device__ __forceinline__ void gload_lds16(const void* g, void* l) {
  __builtin_amdgcn_global_load_lds((const __attribute__((address_space(1))) void*)g,
                                   (__attribute__((address_space(3))) void*)l,
                                   16, 0, 0);
}

// ---------- prologue 1: x fp32 -> bf16 ----------
__global__ void __launch_bounds__(256) convert_x_kernel(const float* __restrict__ x,
                                                        __bf16* __restrict__ a) {
  size_t i = ((size_t)blockIdx.x * 256u + threadIdx.x) * 8u;
  f32x4 v0 = *(const f32x4*)(x + i);
  f32x4 v1 = *(const f32x4*)(x + i + 4);
  bf16x8 o;
  o[0] = (__bf16)v0[0]; o[1] = (__bf16)v0[1]; o[2] = (__bf16)v0[2]; o[3] = (__bf16)v0[3];
  o[4] = (__bf16)v1[0]; o[5] = (__bf16)v1[1]; o[6] = (__bf16)v1[2]; o[7] = (__bf16)v1[3];
  *(bf16x8*)(a + i) = o;
}

// ---------- prologue 2: AWQ dequant -> Wt bf16 [N][K] (transposed via LDS) ----------
__global__ void __launch_bounds__(256) dequant_kernel(const int* __restrict__ qw,
                                                      const int* __restrict__ qz,
                                                      const float* __restrict__ sc,
                                                      __bf16* __restrict__ wt) {
  constexpr int SH[8] = {0, 16, 4, 20, 8, 24, 12, 28};  // AWQ [0,4,1,5,2,6,3,7]*4
  __shared__ __bf16 tile[64][72];
  const int bid = blockIdx.x;
  const int tk = bid & 63;
  const int tn = bid >> 6;
  const int k0 = tk * 64;
  const int c0 = tn * 8;
  const int t = threadIdx.x;
#pragma unroll
  for (int r = 0; r < 2; ++r) {
    int idx = r * 256 + t;
    int kk = idx >> 3;
    int cc = idx & 7;
    int k = k0 + kk;
    int c = c0 + cc;
    uint32_t q  = (uint32_t)qw[(size_t)k * NCOL + c];
    int g = k >> 7;
    uint32_t zq = (uint32_t)qz[(size_t)g * NCOL + c];
    const float* s = sc + (size_t)g * N_DIM + (size_t)c * 8;
#pragma unroll
    for (int j = 0; j < 8; ++j) {
      int wv = (int)((q >> SH[j]) & 15u) - (int)((zq >> SH[j]) & 15u);
      tile[cc * 8 + j][kk] = (__bf16)((float)wv * s[j]);
    }
  }
  __syncthreads();
  const int n0 = tn * 64;
#pragma unroll
  for (int r = 0; r < 2; ++r) {
    int idx = r * 256 + t;
    int row = idx >> 3;
    int kc = idx & 7;
    bf16x8 v = *(const bf16x8*)&tile[row][kc * 8];
    *(bf16x8*)(wt + (size_t)(n0 + row) * K_DIM + k0 + kc * 8) = v;
  }
}

// ---------- main GEMM: 64(M) x 128(N) tile, BK=64, simple 2-barrier loop ----------
// 2 waves (128 thr), wave w owns 64x64 at n-half w; A (64 rows) shared.
// Per wave per kt: 16 ds_read_b128 + 32 MFMA (same R1 ratio; steady ~0.64,
// LDS-read-BW-bound).  LDS 24KB (A 8KB + B 16KB) -> 6 blocks/CU; combined regs
// ~124 (64 AGPR acc + ~60 V) -> 4 waves/SIMD available -> 12 waves/CU = 3/SIMD
// from 3 independent blocks (R1-grade barrier hiding).
// Grid = 32*86 = 2752 on 1536 slots -> 2 rounds, util 0.896 (vs 0.672 in R1-R5:
// the dominant recoverable loss all along).
// Granule-XOR swizzle (verified 0 conflicts R1-R5): row r, granule g stored at
// physical (g^(r&7)); linear gload dest + inverse-swizzled source (rule #21).
__global__ void __launch_bounds__(128, 4) wq_gemm_kernel(
    const __bf16* __restrict__ A,    // [M][K] bf16
    const __bf16* __restrict__ Wt,   // [N][K] bf16
    const float* __restrict__ bias,
    float* __restrict__ out)
{
  __shared__ char As[8192];    // 64 rows x 64 bf16 (128B rows)
  __shared__ char Bs[16384];   // 128 rows x 64 bf16

  const int nwg = gridDim.x;   // 2752
  int bid = blockIdx.x;
  if ((nwg & 7) == 0) {                 // XCD-aware swizzle (2752 % 8 == 0, bijective)
    const int cpx = nwg >> 3;
    bid = (bid & 7) * cpx + (bid >> 3);
  }
  const int bm = bid & 31;              // m-fastest: 32 consecutive blocks share one
  const int bn = bid >> 5;              // B-panel (1MB, L2-hot); A streams from L3
  const int m0 = bm * 64;
  const int n0 = bn * 128;

  const int t = threadIdx.x;   // 0..127
  const int lane = t & 63;
  const int w = t >> 6;        // 0..1 (n-half)
  const int lrow = lane & 15;
  const int lk = lane >> 4;

  // staging source offsets: dest byte cid*16 (cid = i*128+t); decode
  // rp = cid>>3 = i*16 + (t>>3), gl = (t&7)^((t>>3)&7)  (i-independent!)
  const int gl = (t & 7) ^ ((t >> 3) & 7);
  const uint32_t off0 = (uint32_t)(t >> 3) * K_DIM + (uint32_t)gl * 8;
  const __bf16* pA = A  + (size_t)m0 * K_DIM + off0;
  const __bf16* pB = Wt + (size_t)n0 * K_DIM + off0;
  const int w1024 = w * 1024;

  f32x4 acc[4][4];
#pragma unroll
  for (int i = 0; i < 4; ++i)
#pragma unroll
    for (int j = 0; j < 4; ++j) acc[i][j] = (f32x4){0.f, 0.f, 0.f, 0.f};

  // compute-side bases (row&7 == lrow&7 since 16 | frag row stride)
  const char* abase = As + lrow * 128;
  const char* bbase = Bs + w * 8192 + lrow * 128;
  const int gk0 = (lk ^ (lrow & 7)) << 4;        // kk=0 granule byte offset
  const int gk1 = ((4 + lk) ^ (lrow & 7)) << 4;  // kk=1

  for (int kt = 0; kt < 64; ++kt) {
    __syncthreads();   // previous tile's compute done; LDS reusable
#pragma unroll
    for (int i = 0; i < 4; ++i)    // A: 4 rounds of 2KB (rows 16i..16i+15)
      gload_lds16(pA + (size_t)i * (16 * K_DIM), As + i * 2048 + w1024);
#pragma unroll
    for (int i = 0; i < 8; ++i)    // B: 8 rounds
      gload_lds16(pB + (size_t)i * (16 * K_DIM), Bs + i * 2048 + w1024);
    pA += 64; pB += 64;
    __syncthreads();   // compiler drains vmcnt(0): staged tile visible

#pragma unroll
    for (int kk = 0; kk < 2; ++kk) {
      const int g = kk ? gk1 : gk0;
      bf16x8 av[4], bv[4];
#pragma unroll
      for (int m = 0; m < 4; ++m) av[m] = *(const bf16x8*)(abase + m * 2048 + g);
#pragma unroll
      for (int n = 0; n < 4; ++n) bv[n] = *(const bf16x8*)(bbase + n * 2048 + g);
#pragma unroll
      for (int m = 0; m < 4; ++m)
#pragma unroll
        for (int n = 0; n < 4; ++n)
          acc[m][n] = __builtin_amdgcn_mfma_f32_16x16x32_bf16(av[m], bv[n], acc[m][n], 0, 0, 0);
    }
  }

  // epilogue: C/D layout col=lane&15, row=(lane>>4)*4+reg (m89-verified, R1-R5-passed)
  const int orow0 = m0 + lk * 4;
  const int ocol0 = n0 + w * 64 + lrow;
#pragma unroll
  for (int n = 0; n < 4; ++n) {
    const int col = ocol0 + n * 16;
    const float bv = bias[col];
#pragma unroll
    for (int m = 0; m < 4; ++m) {
      float* po = out + (size_t)(orow0 + m * 16) * N_DIM + col;
      po[0]                 = acc[m][n][0] + bv;
      po[(size_t)N_DIM]     = acc[m][n][1] + bv;
      po[2 * (size_t)N_DIM] = acc[m][n][2] + bv;
      po[3 * (size_t)N_DIM] = acc[m][n][3] + bv;
    }
  }
}

extern "C" void kernel_launch(void* const* d_in, const int* in_sizes, int n_in,
                              void* d_out, int out_size, void* d_ws, size_t ws_size,
                              hipStream_t stream) {
  const float* x    = (const float*)d_in[0];
  const int* qw     = (const int*)d_in[1];
  const int* qz     = (const int*)d_in[2];
  const float* sc   = (const float*)d_in[3];
  const float* bias = (const float*)d_in[4];
  float* out = (float*)d_out;

  const int M = in_sizes[0] / K_DIM;        // 2048
  const int grid = (M / 64) * (N_DIM / 128);  // 32 * 86 = 2752 (divisible by 8)

  const size_t abytes = (size_t)M * K_DIM * 2;
  __bf16* Aw = (__bf16*)d_ws;
  __bf16* Wt = (__bf16*)((char*)d_ws + abytes);

  convert_x_kernel<<<(M * K_DIM) / 2048, 256, 0, stream>>>(x, Aw);
  dequant_kernel<<<(K_DIM / 64) * (N_DIM / 64), 256, 0, stream>>>(qw, qz, sc, Wt);

  wq_gemm_kernel<<<grid, 128, 0, stream>>>(Aw, Wt, bias, out);
}

// Round 7
// 228.630 us; speedup vs baseline: 1.2416x; 1.2416x over previous
//
#include <hip/hip_runtime.h>
#include <stdint.h>

#define K_DIM 4096
#define N_DIM 11008
#define NCOL  1376   // N/8

typedef __attribute__((ext_vector_type(4))) float  f32x4;
typedef __attribute__((ext_vector_type(8))) __bf16 bf16x8;

__device__ __forceinline__ void gload_lds16(const void* g, void* l) {
  __builtin_amdgcn_global_load_lds((const __attribute__((address_space(1))) void*)g,
                                   (__attribute__((address_space(3))) void*)l,
                                   16, 0, 0);
}

// ---------- prologue 1: x fp32 -> bf16 ----------
__global__ void __launch_bounds__(256) convert_x_kernel(const float* __restrict__ x,
                                                        __bf16* __restrict__ a) {
  size_t i = ((size_t)blockIdx.x * 256u + threadIdx.x) * 8u;
  f32x4 v0 = *(const f32x4*)(x + i);
  f32x4 v1 = *(const f32x4*)(x + i + 4);
  bf16x8 o;
  o[0] = (__bf16)v0[0]; o[1] = (__bf16)v0[1]; o[2] = (__bf16)v0[2]; o[3] = (__bf16)v0[3];
  o[4] = (__bf16)v1[0]; o[5] = (__bf16)v1[1]; o[6] = (__bf16)v1[2]; o[7] = (__bf16)v1[3];
  *(bf16x8*)(a + i) = o;
}

// ---------- prologue 2: AWQ dequant -> Wt bf16 [N][K] (transposed via LDS) ----------
__global__ void __launch_bounds__(256) dequant_kernel(const int* __restrict__ qw,
                                                      const int* __restrict__ qz,
                                                      const float* __restrict__ sc,
                                                      __bf16* __restrict__ wt) {
  constexpr int SH[8] = {0, 16, 4, 20, 8, 24, 12, 28};  // AWQ [0,4,1,5,2,6,3,7]*4
  __shared__ __bf16 tile[64][72];
  const int bid = blockIdx.x;
  const int tk = bid & 63;
  const int tn = bid >> 6;
  const int k0 = tk * 64;
  const int c0 = tn * 8;
  const int t = threadIdx.x;
#pragma unroll
  for (int r = 0; r < 2; ++r) {
    int idx = r * 256 + t;
    int kk = idx >> 3;
    int cc = idx & 7;
    int k = k0 + kk;
    int c = c0 + cc;
    uint32_t q  = (uint32_t)qw[(size_t)k * NCOL + c];
    int g = k >> 7;
    uint32_t zq = (uint32_t)qz[(size_t)g * NCOL + c];
    const float* s = sc + (size_t)g * N_DIM + (size_t)c * 8;
#pragma unroll
    for (int j = 0; j < 8; ++j) {
      int wv = (int)((q >> SH[j]) & 15u) - (int)((zq >> SH[j]) & 15u);
      tile[cc * 8 + j][kk] = (__bf16)((float)wv * s[j]);
    }
  }
  __syncthreads();
  const int n0 = tn * 64;
#pragma unroll
  for (int r = 0; r < 2; ++r) {
    int idx = r * 256 + t;
    int row = idx >> 3;
    int kc = idx & 7;
    bf16x8 v = *(const bf16x8*)&tile[row][kc * 8];
    *(bf16x8*)(wt + (size_t)(n0 + row) * K_DIM + k0 + kc * 8) = v;
  }
}

// ---------- main GEMM: 128x128 tile, BK=64 — R1 structure, occupancy-shaped ----------
// 4 waves (2M x 2N), per-wave 64x64 = 4x4 frags of 16x16x32 bf16 MFMA.
// R1 decomposition (corrected in R6 post-mortem): steady MfmaUtil = 64%
// (LDS-read-BW cap ~80% minus barrier drain), loss was GRID CONVOY: regs 124
// -> 4 blk/CU capacity -> grid 1376 over 1024 slots = 0.672 util.
// Fix: inflate LDS to 48KB (dynamic; 32KB used) -> exactly 3 blk/CU -> 768
// slots, 2 rounds, util = 1376/1536 = 0.896. 12 waves/CU keeps barrier hiding.
// Granule-XOR swizzle (0 conflicts R1-R6): row r, granule g at physical
// g^(r&7); linear gload dest + inverse-swizzled global source (rule #21).
__global__ void __launch_bounds__(256, 3) wq_gemm_kernel(
    const __bf16* __restrict__ A,    // [M][K] bf16
    const __bf16* __restrict__ Wt,   // [N][K] bf16
    const float* __restrict__ bias,
    float* __restrict__ out,
    const int Mblk)
{
  extern __shared__ char lds[];      // 49152 allocated; As = lds[0:16K), Bs = [16K:32K)
  char* As = lds;
  char* Bs = lds + 16384;

  const int nwg = gridDim.x;
  int bid = blockIdx.x;
  if ((nwg & 7) == 0) {                 // XCD-aware swizzle (1376 % 8 == 0, bijective)
    const int cpx = nwg >> 3;
    bid = (bid & 7) * cpx + (bid >> 3);
  }
  const int bm = bid % Mblk;            // m-fastest: XCD chunk reuses B panels in L2
  const int bn = bid / Mblk;
  const int m0 = bm * 128;
  const int n0 = bn * 128;

  const int t = threadIdx.x;
  const int lane = t & 63;
  const int w = t >> 6;      // 0..3
  const int wr = w >> 1;     // 0..1  (M half)
  const int wc = w & 1;      // 0..1  (N half)
  const int lrow = lane & 15;
  const int lk = lane >> 4;

  // staging source offsets: round i, cid = i*256+t; rp = cid>>3 (0..127),
  // gl = (cid&7)^(rp&7) (inverse-swizzled source granule); dest = cid*16 linear
  const int gl = (t & 7) ^ ((t >> 3) & 7);   // i contributes multiples of 32 to rp: &7 unaffected
  const uint32_t off0 = (uint32_t)(t >> 3) * K_DIM + (uint32_t)gl * 8;
  const __bf16* pA = A  + (size_t)m0 * K_DIM + off0;
  const __bf16* pB = Wt + (size_t)n0 * K_DIM + off0;
  const int w1024 = w * 1024;

  f32x4 acc[4][4];
#pragma unroll
  for (int i = 0; i < 4; ++i)
#pragma unroll
    for (int j = 0; j < 4; ++j) acc[i][j] = (f32x4){0.f, 0.f, 0.f, 0.f};

  // compute-side bases (row&7 == lrow&7 since frag row strides are multiples of 16)
  const char* abase = As + (wr * 64 + lrow) * 128;
  const char* bbase = Bs + (wc * 64 + lrow) * 128;
  const int gk0 = (lk ^ (lrow & 7)) << 4;        // kk=0 granule byte offset
  const int gk1 = ((4 + lk) ^ (lrow & 7)) << 4;  // kk=1

  for (int kt = 0; kt < 64; ++kt) {
    __syncthreads();   // previous tile's compute done; LDS reusable
#pragma unroll
    for (int i = 0; i < 4; ++i)    // A: 4 rounds (rows 32i .. 32i+31)
      gload_lds16(pA + (size_t)i * (32 * K_DIM), As + i * 4096 + w1024);
#pragma unroll
    for (int i = 0; i < 4; ++i)    // B: 4 rounds
      gload_lds16(pB + (size_t)i * (32 * K_DIM), Bs + i * 4096 + w1024);
    pA += 64; pB += 64;
    __syncthreads();   // compiler drains vmcnt(0): staged tile visible

#pragma unroll
    for (int kk = 0; kk < 2; ++kk) {
      const int g = kk ? gk1 : gk0;
      bf16x8 av[4], bv[4];
#pragma unroll
      for (int m = 0; m < 4; ++m) av[m] = *(const bf16x8*)(abase + m * 2048 + g);
#pragma unroll
      for (int n = 0; n < 4; ++n) bv[n] = *(const bf16x8*)(bbase + n * 2048 + g);
#pragma unroll
      for (int m = 0; m < 4; ++m)
#pragma unroll
        for (int n = 0; n < 4; ++n)
          acc[m][n] = __builtin_amdgcn_mfma_f32_16x16x32_bf16(av[m], bv[n], acc[m][n], 0, 0, 0);
    }
  }

  // epilogue: C/D layout col=lane&15, row=(lane>>4)*4+reg (m89-verified, R1-R6-passed)
  const int orow0 = m0 + wr * 64 + lk * 4;
  const int ocol0 = n0 + wc * 64 + lrow;
#pragma unroll
  for (int n = 0; n < 4; ++n) {
    const int col = ocol0 + n * 16;
    const float bv = bias[col];
#pragma unroll
    for (int m = 0; m < 4; ++m) {
      float* po = out + (size_t)(orow0 + m * 16) * N_DIM + col;
      po[0]                 = acc[m][n][0] + bv;
      po[(size_t)N_DIM]     = acc[m][n][1] + bv;
      po[2 * (size_t)N_DIM] = acc[m][n][2] + bv;
      po[3 * (size_t)N_DIM] = acc[m][n][3] + bv;
    }
  }
}

extern "C" void kernel_launch(void* const* d_in, const int* in_sizes, int n_in,
                              void* d_out, int out_size, void* d_ws, size_t ws_size,
                              hipStream_t stream) {
  const float* x    = (const float*)d_in[0];
  const int* qw     = (const int*)d_in[1];
  const int* qz     = (const int*)d_in[2];
  const float* sc   = (const float*)d_in[3];
  const float* bias = (const float*)d_in[4];
  float* out = (float*)d_out;

  const int M = in_sizes[0] / K_DIM;        // 2048
  const int Mblk = M / 128;                 // 16
  const int grid = Mblk * (N_DIM / 128);    // 1376 (divisible by 8)

  const size_t abytes = (size_t)M * K_DIM * 2;
  __bf16* Aw = (__bf16*)d_ws;
  __bf16* Wt = (__bf16*)((char*)d_ws + abytes);

  convert_x_kernel<<<(M * K_DIM) / 2048, 256, 0, stream>>>(x, Aw);
  dequant_kernel<<<(K_DIM / 64) * (N_DIM / 64), 256, 0, stream>>>(qw, qz, sc, Wt);

  hipFuncSetAttribute((const void*)wq_gemm_kernel,
                      hipFuncAttributeMaxDynamicSharedMemorySize, 49152);
  // 49152 dynamic LDS (32KB used): caps residency at 3 blocks/CU so the
  // 1376-block grid runs 2 rounds at 0.896 utilization (vs 0.672 at 4 blk/CU).
  wq_gemm_kernel<<<grid, 256, 49152, stream>>>(Aw, Wt, bias, out, Mblk);
}